// Round 3
// baseline (733.177 us; speedup 1.0000x reference)
//
#include <hip/hip_runtime.h>

// Problem constants
constexpr int Bn   = 32;
constexpr int CIN  = 64;
constexpr int Lx   = 8192;
constexpr int L1   = 8190;   // length after kw=3,d=1 VALID conv
constexpr int LOUT = 8186;   // final output length
constexpr int NCH  = 384;    // 3 * 128 output channels

constexpr int TB = 512;      // threads per block (8 waves)
constexpr int TT = 256;      // time-tile per block
constexpr int NTILES = (LOUT + TT - 1) / TT;  // 32

// LDS array widths (all rows 16B aligned: width*4 % 16 == 0)
constexpr int W7v   = TT + 4;   // h7   covers s in [t0,   t0+TT+4)
constexpr int W10Av = TT + 8;   // h10a covers s in [t0-4, t0+TT+4)
constexpr int W15Av = TT + 12;  // h15a covers s in [t0-8, t0+TT+4)
constexpr int W10Bv = TT + 4;   // h10b covers u in [t0-4, t0+TT)
constexpr int W15Bv = TT + 8;   // h15b covers u in [t0-8, t0+TT)
constexpr int NA_MAX = TT + 12; // stage-1 position count (268)

typedef float v2f __attribute__((ext_vector_type(2)));  // clang vector: ok for nontemporal builtin

// Pre-transpose stage-1 weights into ws: layout [ci][64] with first 54 =
// (k,j) -> k*3+j, k = 0..5: w7_1 row k, 6..11: w10_1, 12..17: w15_1.
__global__ void prep_weights(const float* __restrict__ w7_1,
                             const float* __restrict__ w10_1,
                             const float* __restrict__ w15_1,
                             float* __restrict__ ws) {
    int idx = blockIdx.x * blockDim.x + threadIdx.x;
    if (idx >= 64 * 54) return;
    int ci = idx / 54, r = idx % 54;
    int k = r / 3, j = r % 3;
    const float* src = (k < 6) ? w7_1 : ((k < 12) ? w10_1 : w15_1);
    int kk = (k < 6) ? k : ((k < 12) ? k - 6 : k - 12);
    ws[ci * 64 + r] = src[kk * 192 + ci * 3 + j];
}

// relu + nontemporal streaming store of 2 consecutive t (t even, op 8B-aligned)
__device__ __forceinline__ void store2(float* __restrict__ op, int t,
                                       float a0, float a1) {
    a0 = fmaxf(a0, 0.f); a1 = fmaxf(a1, 0.f);
    if (t + 1 < LOUT) {
        v2f v2; v2.x = a0; v2.y = a1;
        __builtin_nontemporal_store(v2, (v2f*)(op + t));
    } else if (t < LOUT) {
        __builtin_nontemporal_store(a0, op + t);
    }
}

// 512-thread blocks on the round-0 grid: 1024 blocks * 8 waves = 32 waves/CU
// (8/SIMD, the HW max) with NO added redundant global traffic. Stage-1 splits
// the 18 channels across thread-halves (both halves read the same x window
// through L1); stage-3 does 2 positions/lane so each wave-uniform weight
// s_load still feeds 36 FMAs. VGPR must stay <=64 for 8 waves/SIMD.
__global__ __launch_bounds__(TB, 8)
void fused_inception(const float* __restrict__ x,
                     const float* __restrict__ wS1,   // d_ws, [64][64]
                     const float* __restrict__ w7_3,
                     const float* __restrict__ w10_3,
                     const float* __restrict__ w10_5,
                     const float* __restrict__ w15_3,
                     const float* __restrict__ w15_5,
                     float* __restrict__ out) {
    __shared__ float h7  [6 * W7v];
    __shared__ float h10a[6 * W10Av];
    __shared__ float h15a[6 * W15Av];
    __shared__ float h10b[6 * W10Bv];
    __shared__ float h15b[6 * W15Bv];

    const int tid  = threadIdx.x;
    const int tile = blockIdx.x;
    const int b    = blockIdx.y;
    const int t0   = tile * TT;
    const float* xb = x + (size_t)b * CIN * Lx;

    // ---------------- stage 1: three 64->6 convs (kw=3, d=1) ----------------
    // half 0 computes channels 0..8 (h7[0..5] + h10a[0..2]);
    // half 1 computes channels 9..17 (h10a[3..5] + h15a[0..5]).
    {
        const int half = tid >> 8;         // 0 or 1
        const int q    = tid & 255;
        for (int p = q; p < NA_MAX; p += 256) {
            const int s = t0 - 8 + p;
            float a[9];
            #pragma unroll
            for (int k = 0; k < 9; ++k) a[k] = 0.f;
            if (s >= 0 && s < L1) {
                const float* xr = xb + s;
                const float* wr = wS1 + half * 27;   // uniform -> s_load
                for (int ci = 0; ci < CIN; ++ci) {
                    const float x0 = xr[0];
                    const float x1 = xr[1];
                    const float x2 = xr[2];
                    #pragma unroll
                    for (int k = 0; k < 9; ++k) {
                        a[k] = fmaf(wr[k * 3 + 0], x0, a[k]);
                        a[k] = fmaf(wr[k * 3 + 1], x1, a[k]);
                        a[k] = fmaf(wr[k * 3 + 2], x2, a[k]);
                    }
                    xr += Lx;
                    wr += 64;
                }
                #pragma unroll
                for (int k = 0; k < 9; ++k) a[k] = fmaxf(a[k], 0.f);
            }
            if (half == 0) {
                if (p >= 8) {
                    #pragma unroll
                    for (int c = 0; c < 6; ++c) h7[c * W7v + (p - 8)] = a[c];
                }
                if (p >= 4) {
                    #pragma unroll
                    for (int c = 0; c < 3; ++c) h10a[c * W10Av + (p - 4)] = a[6 + c];
                }
            } else {
                if (p >= 4) {
                    #pragma unroll
                    for (int c = 0; c < 3; ++c) h10a[(3 + c) * W10Av + (p - 4)] = a[c];
                }
                #pragma unroll
                for (int c = 0; c < 6; ++c) h15a[c * W15Av + p] = a[3 + c];
            }
        }
    }
    __syncthreads();

    // ---------------- stage 2: mid 6->6 convs (kw=3, d=2), halves split ----
    if (tid < 256) {
        for (int p = tid; p < W10Bv; p += 256) {
            const int u = t0 - 4 + p;
            float v[18];
            #pragma unroll
            for (int c = 0; c < 6; ++c)
                #pragma unroll
                for (int j = 0; j < 3; ++j)
                    v[c * 3 + j] = h10a[c * W10Av + p + 2 * j];
            #pragma unroll
            for (int k = 0; k < 6; ++k) {
                float acc = 0.f;
                #pragma unroll
                for (int r = 0; r < 18; ++r)
                    acc = fmaf(w10_3[k * 18 + r], v[r], acc);
                h10b[k * W10Bv + p] = (u >= 0) ? fmaxf(acc, 0.f) : 0.f;  // causal
            }
        }
    } else {
        for (int p = tid - 256; p < W15Bv; p += 256) {
            const int u = t0 - 8 + p;
            float v[18];
            #pragma unroll
            for (int c = 0; c < 6; ++c)
                #pragma unroll
                for (int j = 0; j < 3; ++j)
                    v[c * 3 + j] = h15a[c * W15Av + p + 2 * j];
            #pragma unroll
            for (int k = 0; k < 6; ++k) {
                float acc = 0.f;
                #pragma unroll
                for (int r = 0; r < 18; ++r)
                    acc = fmaf(w15_3[k * 18 + r], v[r], acc);
                h15b[k * W15Bv + p] = (u >= 0) ? fmaxf(acc, 0.f) : 0.f;  // causal
            }
        }
    }
    __syncthreads();

    // ---------------- stage 3: three 6->128 final convs + relu + store -----
    // 2 consecutive t per lane; 4 wave-pairs each own 32 output channels.
    const int tq = tid & 127;       // position-pair index
    const int wv = tid >> 7;        // 0..3 -> 32 oc each
    const int tt = tq * 2;
    const int tglob = t0 + tt;

    // branch 7: kw=3, d=2 over h7; out channels [0,128)
    {
        float v[6][6];
        #pragma unroll
        for (int c = 0; c < 6; ++c) {
            float2 A = *(const float2*)&h7[c * W7v + tt];
            float2 Bv = *(const float2*)&h7[c * W7v + tt + 2];
            float2 Cv = *(const float2*)&h7[c * W7v + tt + 4];
            v[c][0] = A.x; v[c][1] = A.y; v[c][2] = Bv.x;
            v[c][3] = Bv.y; v[c][4] = Cv.x; v[c][5] = Cv.y;
        }
        for (int oi = 0; oi < 32; ++oi) {
            const int oc = wv * 32 + oi;
            const float* wr = w7_3 + oc * 18;      // wave-uniform -> s_load
            float a0 = 0, a1 = 0;
            #pragma unroll
            for (int c = 0; c < 6; ++c)
                #pragma unroll
                for (int j = 0; j < 3; ++j) {
                    const float w = wr[c * 3 + j];
                    a0 = fmaf(w, v[c][0 + 2 * j], a0);
                    a1 = fmaf(w, v[c][1 + 2 * j], a1);
                }
            float* op = out + ((size_t)b * NCH + oc) * LOUT;
            store2(op, tglob, a0, a1);
        }
    }
    // branch 10: kw=2, d=4, causal pad 4 over h10b; out channels [128,256)
    {
        float v[6][4];
        #pragma unroll
        for (int c = 0; c < 6; ++c) {
            float2 A = *(const float2*)&h10b[c * W10Bv + tt];
            float2 Bv = *(const float2*)&h10b[c * W10Bv + tt + 4];
            v[c][0] = A.x; v[c][1] = A.y; v[c][2] = Bv.x; v[c][3] = Bv.y;
        }
        for (int oi = 0; oi < 32; ++oi) {
            const int oc = wv * 32 + oi;
            const float* wr = w10_5 + oc * 12;
            float a0 = 0, a1 = 0;
            #pragma unroll
            for (int c = 0; c < 6; ++c) {
                const float w0 = wr[c * 2 + 0];
                const float w1 = wr[c * 2 + 1];
                a0 = fmaf(w0, v[c][0], a0); a0 = fmaf(w1, v[c][2], a0);
                a1 = fmaf(w0, v[c][1], a1); a1 = fmaf(w1, v[c][3], a1);
            }
            float* op = out + ((size_t)b * NCH + 128 + oc) * LOUT;
            store2(op, tglob, a0, a1);
        }
    }
    // branch 15: kw=3, d=4, causal pad 8 over h15b; out channels [256,384)
    {
        float v[6][6];
        #pragma unroll
        for (int c = 0; c < 6; ++c) {
            float2 A = *(const float2*)&h15b[c * W15Bv + tt];
            float2 Bv = *(const float2*)&h15b[c * W15Bv + tt + 4];
            float2 Cv = *(const float2*)&h15b[c * W15Bv + tt + 8];
            v[c][0] = A.x; v[c][1] = A.y; v[c][2] = Bv.x;
            v[c][3] = Bv.y; v[c][4] = Cv.x; v[c][5] = Cv.y;
        }
        for (int oi = 0; oi < 32; ++oi) {
            const int oc = wv * 32 + oi;
            const float* wr = w15_5 + oc * 18;
            float a0 = 0, a1 = 0;
            #pragma unroll
            for (int c = 0; c < 6; ++c)
                #pragma unroll
                for (int j = 0; j < 3; ++j) {
                    const float w = wr[c * 3 + j];
                    a0 = fmaf(w, v[c][0 + 2 * j], a0);
                    a1 = fmaf(w, v[c][1 + 2 * j], a1);
                }
            float* op = out + ((size_t)b * NCH + 256 + oc) * LOUT;
            store2(op, tglob, a0, a1);
        }
    }
}

extern "C" void kernel_launch(void* const* d_in, const int* in_sizes, int n_in,
                              void* d_out, int out_size, void* d_ws, size_t ws_size,
                              hipStream_t stream) {
    const float* x     = (const float*)d_in[0];
    const float* w7_1  = (const float*)d_in[1];
    const float* w7_3  = (const float*)d_in[2];
    const float* w10_1 = (const float*)d_in[3];
    const float* w10_3 = (const float*)d_in[4];
    const float* w10_5 = (const float*)d_in[5];
    const float* w15_1 = (const float*)d_in[6];
    const float* w15_3 = (const float*)d_in[7];
    const float* w15_5 = (const float*)d_in[8];
    float* out = (float*)d_out;
    float* ws  = (float*)d_ws;   // 64*64 floats = 16 KB used

    prep_weights<<<dim3(14), dim3(256), 0, stream>>>(w7_1, w10_1, w15_1, ws);
    fused_inception<<<dim3(NTILES, Bn), dim3(TB), 0, stream>>>(
        x, ws, w7_3, w10_3, w10_5, w15_3, w15_5, out);
}

// Round 4
// 715.230 us; speedup vs baseline: 1.0251x; 1.0251x over previous
//
#include <hip/hip_runtime.h>

// Problem constants
constexpr int Bn   = 32;
constexpr int CIN  = 64;
constexpr int Lx   = 8192;
constexpr int L1   = 8190;   // length after kw=3,d=1 VALID conv
constexpr int LOUT = 8186;   // final output length
constexpr int NCH  = 384;    // 3 * 128 output channels

constexpr int TB = 512;      // threads per block (8 waves)
constexpr int TT = 256;      // time-tile per block
constexpr int NTILES = (LOUT + TT - 1) / TT;  // 32

// LDS array widths (all rows 16B aligned: width*4 % 16 == 0)
constexpr int W7v   = TT + 4;   // h7   covers s in [t0,   t0+TT+4)
constexpr int W10Av = TT + 8;   // h10a covers s in [t0-4, t0+TT+4)
constexpr int W15Av = TT + 12;  // h15a covers s in [t0-8, t0+TT+4)
constexpr int W10Bv = TT + 4;   // h10b covers u in [t0-4, t0+TT)
constexpr int W15Bv = TT + 8;   // h15b covers u in [t0-8, t0+TT)
constexpr int NA_MAX = TT + 12; // stage-1 position count (268)

typedef float v2f __attribute__((ext_vector_type(2)));  // clang vector type

// Pre-transpose stage-1 weights into ws: layout [ci][64] with first 54 =
// (k,j) -> k*3+j, k = 0..5: w7_1 row k, 6..11: w10_1, 12..17: w15_1.
__global__ void prep_weights(const float* __restrict__ w7_1,
                             const float* __restrict__ w10_1,
                             const float* __restrict__ w15_1,
                             float* __restrict__ ws) {
    int idx = blockIdx.x * blockDim.x + threadIdx.x;
    if (idx >= 64 * 54) return;
    int ci = idx / 54, r = idx % 54;
    int k = r / 3, j = r % 3;
    const float* src = (k < 6) ? w7_1 : ((k < 12) ? w10_1 : w15_1);
    int kk = (k < 6) ? k : ((k < 12) ? k - 6 : k - 12);
    ws[ci * 64 + r] = src[kk * 192 + ci * 3 + j];
}

// relu + nontemporal streaming store of 2 consecutive t (t even, op 8B-aligned)
__device__ __forceinline__ void store2(float* __restrict__ op, int t,
                                       float a0, float a1) {
    a0 = fmaxf(a0, 0.f); a1 = fmaxf(a1, 0.f);
    if (t + 1 < LOUT) {
        v2f v2; v2.x = a0; v2.y = a1;
        __builtin_nontemporal_store(v2, (v2f*)(op + t));
    } else if (t < LOUT) {
        __builtin_nontemporal_store(a0, op + t);
    }
}

// TB=512 on the 1024-block grid. launch_bounds(512,6): VGPR cap ~84 so the
// stage-3 v[6][6] fragment (36 floats) + accumulators stay in registers
// (round-3's (512,8) forced VGPR=32 -> spills -> 400us). 3 blocks/CU =
// 24 waves/CU (LDS 3*31.7KB = 95KB < 160KB).
__global__ __launch_bounds__(TB, 6)
void fused_inception(const float* __restrict__ x,
                     const float* __restrict__ wS1,   // d_ws, [64][64]
                     const float* __restrict__ w7_3,
                     const float* __restrict__ w10_3,
                     const float* __restrict__ w10_5,
                     const float* __restrict__ w15_3,
                     const float* __restrict__ w15_5,
                     float* __restrict__ out) {
    __shared__ float h7  [6 * W7v];
    __shared__ float h10a[6 * W10Av];
    __shared__ float h15a[6 * W15Av];
    __shared__ float h10b[6 * W10Bv];
    __shared__ float h15b[6 * W15Bv];

    const int tid  = threadIdx.x;
    const int tile = blockIdx.x;
    const int b    = blockIdx.y;
    const int t0   = tile * TT;
    const float* xb = x + (size_t)b * CIN * Lx;

    // ---------------- stage 1: three 64->6 convs (kw=3, d=1) ----------------
    // half 0 computes channels 0..8 (h7[0..5] + h10a[0..2]);
    // half 1 computes channels 9..17 (h10a[3..5] + h15a[0..5]).
    {
        const int half = tid >> 8;         // 0 or 1
        const int q    = tid & 255;
        for (int p = q; p < NA_MAX; p += 256) {
            const int s = t0 - 8 + p;
            float a[9];
            #pragma unroll
            for (int k = 0; k < 9; ++k) a[k] = 0.f;
            if (s >= 0 && s < L1) {
                const float* xr = xb + s;
                const float* wr = wS1 + half * 27;   // uniform -> s_load
                for (int ci = 0; ci < CIN; ++ci) {
                    const float x0 = xr[0];
                    const float x1 = xr[1];
                    const float x2 = xr[2];
                    #pragma unroll
                    for (int k = 0; k < 9; ++k) {
                        a[k] = fmaf(wr[k * 3 + 0], x0, a[k]);
                        a[k] = fmaf(wr[k * 3 + 1], x1, a[k]);
                        a[k] = fmaf(wr[k * 3 + 2], x2, a[k]);
                    }
                    xr += Lx;
                    wr += 64;
                }
                #pragma unroll
                for (int k = 0; k < 9; ++k) a[k] = fmaxf(a[k], 0.f);
            }
            if (half == 0) {
                if (p >= 8) {
                    #pragma unroll
                    for (int c = 0; c < 6; ++c) h7[c * W7v + (p - 8)] = a[c];
                }
                if (p >= 4) {
                    #pragma unroll
                    for (int c = 0; c < 3; ++c) h10a[c * W10Av + (p - 4)] = a[6 + c];
                }
            } else {
                if (p >= 4) {
                    #pragma unroll
                    for (int c = 0; c < 3; ++c) h10a[(3 + c) * W10Av + (p - 4)] = a[c];
                }
                #pragma unroll
                for (int c = 0; c < 6; ++c) h15a[c * W15Av + p] = a[3 + c];
            }
        }
    }
    __syncthreads();

    // ---------------- stage 2: mid 6->6 convs (kw=3, d=2), halves split ----
    if (tid < 256) {
        for (int p = tid; p < W10Bv; p += 256) {
            const int u = t0 - 4 + p;
            float v[18];
            #pragma unroll
            for (int c = 0; c < 6; ++c)
                #pragma unroll
                for (int j = 0; j < 3; ++j)
                    v[c * 3 + j] = h10a[c * W10Av + p + 2 * j];
            #pragma unroll
            for (int k = 0; k < 6; ++k) {
                float acc = 0.f;
                #pragma unroll
                for (int r = 0; r < 18; ++r)
                    acc = fmaf(w10_3[k * 18 + r], v[r], acc);
                h10b[k * W10Bv + p] = (u >= 0) ? fmaxf(acc, 0.f) : 0.f;  // causal
            }
        }
    } else {
        for (int p = tid - 256; p < W15Bv; p += 256) {
            const int u = t0 - 8 + p;
            float v[18];
            #pragma unroll
            for (int c = 0; c < 6; ++c)
                #pragma unroll
                for (int j = 0; j < 3; ++j)
                    v[c * 3 + j] = h15a[c * W15Av + p + 2 * j];
            #pragma unroll
            for (int k = 0; k < 6; ++k) {
                float acc = 0.f;
                #pragma unroll
                for (int r = 0; r < 18; ++r)
                    acc = fmaf(w15_3[k * 18 + r], v[r], acc);
                h15b[k * W15Bv + p] = (u >= 0) ? fmaxf(acc, 0.f) : 0.f;  // causal
            }
        }
    }
    __syncthreads();

    // ---------------- stage 3: three 6->128 final convs + relu + store -----
    // 2 consecutive t per lane; 4 wave-pairs each own 32 output channels.
    const int tq = tid & 127;       // position-pair index
    const int wv = tid >> 7;        // 0..3 -> 32 oc each
    const int tt = tq * 2;
    const int tglob = t0 + tt;

    // branch 7: kw=3, d=2 over h7; out channels [0,128)
    {
        float v[6][6];
        #pragma unroll
        for (int c = 0; c < 6; ++c) {
            float2 A = *(const float2*)&h7[c * W7v + tt];
            float2 Bv = *(const float2*)&h7[c * W7v + tt + 2];
            float2 Cv = *(const float2*)&h7[c * W7v + tt + 4];
            v[c][0] = A.x; v[c][1] = A.y; v[c][2] = Bv.x;
            v[c][3] = Bv.y; v[c][4] = Cv.x; v[c][5] = Cv.y;
        }
        #pragma unroll 4
        for (int oi = 0; oi < 32; ++oi) {
            const int oc = wv * 32 + oi;
            const float* wr = w7_3 + oc * 18;      // wave-uniform -> s_load
            float a0 = 0, a1 = 0;
            #pragma unroll
            for (int c = 0; c < 6; ++c)
                #pragma unroll
                for (int j = 0; j < 3; ++j) {
                    const float w = wr[c * 3 + j];
                    a0 = fmaf(w, v[c][0 + 2 * j], a0);
                    a1 = fmaf(w, v[c][1 + 2 * j], a1);
                }
            float* op = out + ((size_t)b * NCH + oc) * LOUT;
            store2(op, tglob, a0, a1);
        }
    }
    // branch 10: kw=2, d=4, causal pad 4 over h10b; out channels [128,256)
    {
        float v[6][4];
        #pragma unroll
        for (int c = 0; c < 6; ++c) {
            float2 A = *(const float2*)&h10b[c * W10Bv + tt];
            float2 Bv = *(const float2*)&h10b[c * W10Bv + tt + 4];
            v[c][0] = A.x; v[c][1] = A.y; v[c][2] = Bv.x; v[c][3] = Bv.y;
        }
        #pragma unroll 4
        for (int oi = 0; oi < 32; ++oi) {
            const int oc = wv * 32 + oi;
            const float* wr = w10_5 + oc * 12;
            float a0 = 0, a1 = 0;
            #pragma unroll
            for (int c = 0; c < 6; ++c) {
                const float w0 = wr[c * 2 + 0];
                const float w1 = wr[c * 2 + 1];
                a0 = fmaf(w0, v[c][0], a0); a0 = fmaf(w1, v[c][2], a0);
                a1 = fmaf(w0, v[c][1], a1); a1 = fmaf(w1, v[c][3], a1);
            }
            float* op = out + ((size_t)b * NCH + 128 + oc) * LOUT;
            store2(op, tglob, a0, a1);
        }
    }
    // branch 15: kw=3, d=4, causal pad 8 over h15b; out channels [256,384)
    {
        float v[6][6];
        #pragma unroll
        for (int c = 0; c < 6; ++c) {
            float2 A = *(const float2*)&h15b[c * W15Bv + tt];
            float2 Bv = *(const float2*)&h15b[c * W15Bv + tt + 4];
            float2 Cv = *(const float2*)&h15b[c * W15Bv + tt + 8];
            v[c][0] = A.x; v[c][1] = A.y; v[c][2] = Bv.x;
            v[c][3] = Bv.y; v[c][4] = Cv.x; v[c][5] = Cv.y;
        }
        #pragma unroll 4
        for (int oi = 0; oi < 32; ++oi) {
            const int oc = wv * 32 + oi;
            const float* wr = w15_5 + oc * 18;
            float a0 = 0, a1 = 0;
            #pragma unroll
            for (int c = 0; c < 6; ++c)
                #pragma unroll
                for (int j = 0; j < 3; ++j) {
                    const float w = wr[c * 3 + j];
                    a0 = fmaf(w, v[c][0 + 2 * j], a0);
                    a1 = fmaf(w, v[c][1 + 2 * j], a1);
                }
            float* op = out + ((size_t)b * NCH + 256 + oc) * LOUT;
            store2(op, tglob, a0, a1);
        }
    }
}

extern "C" void kernel_launch(void* const* d_in, const int* in_sizes, int n_in,
                              void* d_out, int out_size, void* d_ws, size_t ws_size,
                              hipStream_t stream) {
    const float* x     = (const float*)d_in[0];
    const float* w7_1  = (const float*)d_in[1];
    const float* w7_3  = (const float*)d_in[2];
    const float* w10_1 = (const float*)d_in[3];
    const float* w10_3 = (const float*)d_in[4];
    const float* w10_5 = (const float*)d_in[5];
    const float* w15_1 = (const float*)d_in[6];
    const float* w15_3 = (const float*)d_in[7];
    const float* w15_5 = (const float*)d_in[8];
    float* out = (float*)d_out;
    float* ws  = (float*)d_ws;   // 64*64 floats = 16 KB used

    prep_weights<<<dim3(14), dim3(256), 0, stream>>>(w7_1, w10_1, w15_1, ws);
    fused_inception<<<dim3(NTILES, Bn), dim3(TB), 0, stream>>>(
        x, ws, w7_3, w10_3, w10_5, w15_3, w15_5, out);
}